// Round 1
// baseline (372.239 us; speedup 1.0000x reference)
//
#include <hip/hip_runtime.h>

#define N_IMGS 8
#define C 256
#define H 128
#define W 128
#define R 1024
#define HOUT 14
#define WOUT 14
#define NPOS 196          // HOUT*WOUT
#define HW (H * W)        // 16384
#define IMG_ELEMS (C * HW)

// ---------------------------------------------------------------------------
// Kernel 1: NCHW -> NHWC transpose (per image: (C, HW) -> (HW, C))
// 32x32 tile via LDS, +1 pad to kill bank conflicts. Coalesced both sides.
// ---------------------------------------------------------------------------
__global__ __launch_bounds__(256) void transpose_nchw_nhwc(
    const float* __restrict__ in, float* __restrict__ out) {
  __shared__ float tile[32][33];
  const int n   = blockIdx.z;
  const int hw0 = blockIdx.x * 32;
  const int c0  = blockIdx.y * 32;
  const float* inp = in + (size_t)n * IMG_ELEMS;
  float* outp      = out + (size_t)n * IMG_ELEMS;
  const int tx = threadIdx.x;  // 0..31
  const int ty = threadIdx.y;  // 0..7

#pragma unroll
  for (int i = 0; i < 4; ++i) {
    int cc = ty + i * 8;
    tile[cc][tx] = inp[(size_t)(c0 + cc) * HW + hw0 + tx];
  }
  __syncthreads();
#pragma unroll
  for (int i = 0; i < 4; ++i) {
    int hh = ty + i * 8;
    outp[(size_t)(hw0 + hh) * C + c0 + tx] = tile[tx][hh];
  }
}

// ---------------------------------------------------------------------------
// Kernel 2: RoI Align. One block per roi, one thread per channel.
// First 196 threads precompute corner offsets + weights into LDS.
// Main loop: 4 coalesced gathers per position, float4 stores per channel row.
// Template: NHWC=true reads the transposed workspace copy; false = fallback
// reading NCHW directly (correct but slow) if ws is too small.
// ---------------------------------------------------------------------------
template <bool NHWC>
__global__ __launch_bounds__(256) void roi_align_kernel(
    const float* __restrict__ feats, const float* __restrict__ rois,
    float* __restrict__ out) {
  __shared__ int4   s_off[NPOS];
  __shared__ float4 s_w[NPOS];

  const int r   = blockIdx.x;
  const int tid = threadIdx.x;

  const float bf = rois[r * 5 + 0];
  const float x1 = rois[r * 5 + 1];
  const float y1 = rois[r * 5 + 2];
  const float x2 = rois[r * 5 + 3];
  const float y2 = rois[r * 5 + 4];
  const int   n  = (int)bf;

  if (tid < NPOS) {
    const int ph = tid / WOUT;
    const int pw = tid - ph * WOUT;
    const float px_rel = (pw + 0.5f) / (float)WOUT;
    const float py_rel = (ph + 0.5f) / (float)HOUT;
    const float x_abs = px_rel * (x2 - x1) + x1;
    const float y_abs = py_rel * (y2 - y1) + y1;
    // rx = x_abs / W * 0.25 ; px = rx * W - 0.5  ==  x_abs * 0.25 - 0.5
    const float px = x_abs * 0.25f - 0.5f;
    const float py = y_abs * 0.25f - 0.5f;
    const float x0f = floorf(px);
    const float y0f = floorf(py);
    const float lx = px - x0f, ly = py - y0f;   // (px - x0f), (py - y0f)
    const float hx = 1.0f - lx, hy = 1.0f - ly; // (x0f+1-px), (y0f+1-py)
    const int ix0 = (int)x0f;
    const int iy0 = (int)y0f;
    const int ix1 = ix0 + 1;
    const int iy1 = iy0 + 1;
    // Reference pads with zeros and clips into the pad -> OOB corners
    // contribute exactly 0. Reproduce by zeroing the weight.
    const bool vx0 = (ix0 >= 0) && (ix0 < W);
    const bool vx1 = (ix1 >= 0) && (ix1 < W);
    const bool vy0 = (iy0 >= 0) && (iy0 < H);
    const bool vy1 = (iy1 >= 0) && (iy1 < H);
    const int cx0 = min(max(ix0, 0), W - 1);
    const int cx1 = min(max(ix1, 0), W - 1);
    const int cy0 = min(max(iy0, 0), H - 1);
    const int cy1 = min(max(iy1, 0), H - 1);
    int4 o;
    o.x = cy0 * W + cx0;  // (y0, x0) -> weight wa = hx*hy
    o.y = cy1 * W + cx0;  // (y1, x0) -> weight wb = hx*ly
    o.z = cy0 * W + cx1;  // (y0, x1) -> weight wc = lx*hy
    o.w = cy1 * W + cx1;  // (y1, x1) -> weight wd = lx*ly
    float4 w4;
    w4.x = (vx0 && vy0) ? hx * hy : 0.0f;
    w4.y = (vx0 && vy1) ? hx * ly : 0.0f;
    w4.z = (vx1 && vy0) ? lx * hy : 0.0f;
    w4.w = (vx1 && vy1) ? lx * ly : 0.0f;
    s_off[tid] = o;
    s_w[tid]   = w4;
  }
  __syncthreads();

  const int c = tid;  // channel
  const float* img = feats + (size_t)n * IMG_ELEMS;
  float* outp = out + ((size_t)r * C + c) * NPOS;

#pragma unroll 1
  for (int p4 = 0; p4 < NPOS / 4; ++p4) {
    float res[4];
#pragma unroll
    for (int k = 0; k < 4; ++k) {
      const int p = p4 * 4 + k;
      const int4   o = s_off[p];
      const float4 w = s_w[p];
      float va, vb, vc, vd;
      if (NHWC) {
        va = img[(size_t)o.x * C + c];
        vb = img[(size_t)o.y * C + c];
        vc = img[(size_t)o.z * C + c];
        vd = img[(size_t)o.w * C + c];
      } else {
        const float* plane = img + (size_t)c * HW;
        va = plane[o.x];
        vb = plane[o.y];
        vc = plane[o.z];
        vd = plane[o.w];
      }
      res[k] = va * w.x + vb * w.y + vc * w.z + vd * w.w;
    }
    float4 rv = make_float4(res[0], res[1], res[2], res[3]);
    *reinterpret_cast<float4*>(outp + p4 * 4) = rv;  // 784B row: 16B-aligned
  }
}

extern "C" void kernel_launch(void* const* d_in, const int* in_sizes, int n_in,
                              void* d_out, int out_size, void* d_ws,
                              size_t ws_size, hipStream_t stream) {
  const float* feats = (const float*)d_in[0];
  const float* rois  = (const float*)d_in[1];
  float* out         = (float*)d_out;

  const size_t need = (size_t)N_IMGS * IMG_ELEMS * sizeof(float);
  if (ws_size >= need) {
    float* nhwc = (float*)d_ws;
    dim3 tb(32, 8);
    dim3 tg(HW / 32, C / 32, N_IMGS);
    transpose_nchw_nhwc<<<tg, tb, 0, stream>>>(feats, nhwc);
    roi_align_kernel<true><<<dim3(R), dim3(256), 0, stream>>>(nhwc, rois, out);
  } else {
    // Safety fallback: direct NCHW gathers (uncoalesced but correct).
    roi_align_kernel<false><<<dim3(R), dim3(256), 0, stream>>>(feats, rois, out);
  }
}

// Round 2
// 336.447 us; speedup vs baseline: 1.1064x; 1.1064x over previous
//
#include <hip/hip_runtime.h>

#define N_IMGS 8
#define C 256
#define H 128
#define W 128
#define R 1024
#define HOUT 14
#define WOUT 14
#define NPOS 196          // HOUT*WOUT
#define HW (H * W)        // 16384
#define IMG_ELEMS (C * HW)

// ---------------------------------------------------------------------------
// Kernel 1: NCHW -> NHWC transpose (per image: (C, HW) -> (HW, C))
// 32x32 tile via LDS, +1 pad to kill bank conflicts. Coalesced both sides.
// ---------------------------------------------------------------------------
__global__ __launch_bounds__(256) void transpose_nchw_nhwc(
    const float* __restrict__ in, float* __restrict__ out) {
  __shared__ float tile[32][33];
  const int n   = blockIdx.z;
  const int hw0 = blockIdx.x * 32;
  const int c0  = blockIdx.y * 32;
  const float* inp = in + (size_t)n * IMG_ELEMS;
  float* outp      = out + (size_t)n * IMG_ELEMS;
  const int tx = threadIdx.x;  // 0..31
  const int ty = threadIdx.y;  // 0..7

#pragma unroll
  for (int i = 0; i < 4; ++i) {
    int cc = ty + i * 8;
    tile[cc][tx] = inp[(size_t)(c0 + cc) * HW + hw0 + tx];
  }
  __syncthreads();
#pragma unroll
  for (int i = 0; i < 4; ++i) {
    int hh = ty + i * 8;
    outp[(size_t)(hw0 + hh) * C + c0 + tx] = tile[tx][hh];
  }
}

// ---------------------------------------------------------------------------
// Kernel 2: RoI Align.
// Grid = 2*R blocks of 512 threads. Each block: roi r = blockIdx.x>>1,
// position-half = blockIdx.x&1. Thread tid -> channel c = tid&255,
// position-quarter pg = (half<<1)|(tid>>8). pg 0..2 own 48 positions each,
// pg 3 owns 52. Threads buffer 8 positions (32B) and store two float4s
// back-to-back so L2 lines fill immediately (kills RMW write amplification).
// __launch_bounds__(512, 8): 8 waves/SIMD -> 32 waves/CU (4 blocks), VGPR<=64.
// ---------------------------------------------------------------------------
template <bool NHWC>
__global__ __launch_bounds__(512, 8) void roi_align_kernel(
    const float* __restrict__ feats, const float* __restrict__ rois,
    float* __restrict__ out) {
  __shared__ int4   s_off[NPOS];
  __shared__ float4 s_w[NPOS];

  const int r    = blockIdx.x >> 1;
  const int half = blockIdx.x & 1;
  const int tid  = threadIdx.x;
  const int c    = tid & 255;
  const int pg   = (half << 1) | (tid >> 8);

  const float bf = rois[r * 5 + 0];
  const float x1 = rois[r * 5 + 1];
  const float y1 = rois[r * 5 + 2];
  const float x2 = rois[r * 5 + 3];
  const float y2 = rois[r * 5 + 4];
  const int   n  = (int)bf;

  if (tid < NPOS) {
    const int ph = tid / WOUT;
    const int pw = tid - ph * WOUT;
    const float px_rel = (pw + 0.5f) / (float)WOUT;
    const float py_rel = (ph + 0.5f) / (float)HOUT;
    const float x_abs = px_rel * (x2 - x1) + x1;
    const float y_abs = py_rel * (y2 - y1) + y1;
    // rx = x_abs / W * 0.25 ; px = rx * W - 0.5  ==  x_abs * 0.25 - 0.5
    const float px = x_abs * 0.25f - 0.5f;
    const float py = y_abs * 0.25f - 0.5f;
    const float x0f = floorf(px);
    const float y0f = floorf(py);
    const float lx = px - x0f, ly = py - y0f;
    const float hx = 1.0f - lx, hy = 1.0f - ly;
    const int ix0 = (int)x0f;
    const int iy0 = (int)y0f;
    const int ix1 = ix0 + 1;
    const int iy1 = iy0 + 1;
    // Reference pads with zeros and clips into the pad -> OOB corners
    // contribute exactly 0. Reproduce by zeroing the weight.
    const bool vx0 = (ix0 >= 0) && (ix0 < W);
    const bool vx1 = (ix1 >= 0) && (ix1 < W);
    const bool vy0 = (iy0 >= 0) && (iy0 < H);
    const bool vy1 = (iy1 >= 0) && (iy1 < H);
    const int cx0 = min(max(ix0, 0), W - 1);
    const int cx1 = min(max(ix1, 0), W - 1);
    const int cy0 = min(max(iy0, 0), H - 1);
    const int cy1 = min(max(iy1, 0), H - 1);
    int4 o;
    o.x = cy0 * W + cx0;
    o.y = cy1 * W + cx0;
    o.z = cy0 * W + cx1;
    o.w = cy1 * W + cx1;
    float4 w4;
    w4.x = (vx0 && vy0) ? hx * hy : 0.0f;
    w4.y = (vx0 && vy1) ? hx * ly : 0.0f;
    w4.z = (vx1 && vy0) ? lx * hy : 0.0f;
    w4.w = (vx1 && vy1) ? lx * ly : 0.0f;
    s_off[tid] = o;
    s_w[tid]   = w4;
  }
  __syncthreads();

  const float* img = feats + (size_t)n * IMG_ELEMS;
  float* outp = out + ((size_t)r * C + c) * NPOS;

  const int p_begin = pg * 48;
  const int p_end   = (pg == 3) ? NPOS : p_begin + 48;  // 48,48,48,52

  int p0 = p_begin;
#pragma unroll 1
  for (; p0 + 8 <= p_end; p0 += 8) {
    float res[8];
#pragma unroll
    for (int k = 0; k < 8; ++k) {
      const int p = p0 + k;
      const int4   o = s_off[p];
      const float4 w = s_w[p];
      float va, vb, vc, vd;
      if (NHWC) {
        va = img[(size_t)o.x * C + c];
        vb = img[(size_t)o.y * C + c];
        vc = img[(size_t)o.z * C + c];
        vd = img[(size_t)o.w * C + c];
      } else {
        const float* plane = img + (size_t)c * HW;
        va = plane[o.x];
        vb = plane[o.y];
        vc = plane[o.z];
        vd = plane[o.w];
      }
      res[k] = va * w.x + vb * w.y + vc * w.z + vd * w.w;
    }
    *reinterpret_cast<float4*>(outp + p0)     =
        make_float4(res[0], res[1], res[2], res[3]);
    *reinterpret_cast<float4*>(outp + p0 + 4) =
        make_float4(res[4], res[5], res[6], res[7]);
  }
  if (p0 < p_end) {  // tail of 4 (pg==3 only)
    float res[4];
#pragma unroll
    for (int k = 0; k < 4; ++k) {
      const int p = p0 + k;
      const int4   o = s_off[p];
      const float4 w = s_w[p];
      float va, vb, vc, vd;
      if (NHWC) {
        va = img[(size_t)o.x * C + c];
        vb = img[(size_t)o.y * C + c];
        vc = img[(size_t)o.z * C + c];
        vd = img[(size_t)o.w * C + c];
      } else {
        const float* plane = img + (size_t)c * HW;
        va = plane[o.x];
        vb = plane[o.y];
        vc = plane[o.z];
        vd = plane[o.w];
      }
      res[k] = va * w.x + vb * w.y + vc * w.z + vd * w.w;
    }
    *reinterpret_cast<float4*>(outp + p0) =
        make_float4(res[0], res[1], res[2], res[3]);
  }
}

extern "C" void kernel_launch(void* const* d_in, const int* in_sizes, int n_in,
                              void* d_out, int out_size, void* d_ws,
                              size_t ws_size, hipStream_t stream) {
  const float* feats = (const float*)d_in[0];
  const float* rois  = (const float*)d_in[1];
  float* out         = (float*)d_out;

  const size_t need = (size_t)N_IMGS * IMG_ELEMS * sizeof(float);
  if (ws_size >= need) {
    float* nhwc = (float*)d_ws;
    dim3 tb(32, 8);
    dim3 tg(HW / 32, C / 32, N_IMGS);
    transpose_nchw_nhwc<<<tg, tb, 0, stream>>>(feats, nhwc);
    roi_align_kernel<true><<<dim3(R * 2), dim3(512), 0, stream>>>(nhwc, rois,
                                                                  out);
  } else {
    // Safety fallback: direct NCHW gathers (uncoalesced but correct).
    roi_align_kernel<false><<<dim3(R * 2), dim3(512), 0, stream>>>(feats, rois,
                                                                   out);
  }
}